// Round 1
// baseline (3680.269 us; speedup 1.0000x reference)
//
#include <hip/hip_runtime.h>
#include <math.h>

#define T_ 1024
#define D_ 3
#define H_ 64
#define WPB 4   // waves per block

__device__ __forceinline__ float fast_sigmoid(float x) {
    return __builtin_amdgcn_rcpf(1.0f + __expf(-x));
}
__device__ __forceinline__ float fast_tanh(float x) {
    // tanh(x) = 1 - 2/(exp(2x)+1); exact at extremes, abs err ~1e-7 elsewhere
    float e = __expf(2.0f * x);
    return 1.0f - 2.0f * __builtin_amdgcn_rcpf(e + 1.0f);
}

// One wave per sequence. Lane j owns hidden unit j for BOTH GRU chains
// (chain 0 = x1, chain 1 = x2). Recurrent weights held in registers
// (192 VGPR/lane); h fan-out via wave-private LDS broadcast reads.
__global__ __launch_bounds__(256, 2) void gru_siamese(
    const float* __restrict__ x1, const float* __restrict__ x2,
    const float* __restrict__ W_ih, const float* __restrict__ W_hh,
    const float* __restrict__ b_ih, const float* __restrict__ b_hh,
    const float* __restrict__ W1, const float* __restrict__ b1,
    const float* __restrict__ W2, const float* __restrict__ b2,
    float* __restrict__ out)
{
    const int lane = threadIdx.x & 63;
    const int wave = threadIdx.x >> 6;
    const int seq  = __builtin_amdgcn_readfirstlane((int)(blockIdx.x * WPB + wave));

    __shared__ float lds_h[WPB][2][H_];

    // ---- load loop-invariant weights into registers ----
    float wr[H_], wz[H_], wn[H_];
    {
        const float4* r0 = (const float4*)(W_hh + (0 * H_ + lane) * H_);
        const float4* r1 = (const float4*)(W_hh + (1 * H_ + lane) * H_);
        const float4* r2 = (const float4*)(W_hh + (2 * H_ + lane) * H_);
        #pragma unroll
        for (int k = 0; k < H_ / 4; ++k) {
            float4 a = r0[k], b = r1[k], c = r2[k];
            wr[4*k+0] = a.x; wr[4*k+1] = a.y; wr[4*k+2] = a.z; wr[4*k+3] = a.w;
            wz[4*k+0] = b.x; wz[4*k+1] = b.y; wz[4*k+2] = b.z; wz[4*k+3] = b.w;
            wn[4*k+0] = c.x; wn[4*k+1] = c.y; wn[4*k+2] = c.z; wn[4*k+3] = c.w;
        }
    }
    float wxr[D_], wxz[D_], wxn[D_];
    #pragma unroll
    for (int d = 0; d < D_; ++d) {
        wxr[d] = W_ih[(0 * H_ + lane) * D_ + d];
        wxz[d] = W_ih[(1 * H_ + lane) * D_ + d];
        wxn[d] = W_ih[(2 * H_ + lane) * D_ + d];
    }
    const float brz = b_ih[0*H_ + lane] + b_hh[0*H_ + lane];
    const float bzz = b_ih[1*H_ + lane] + b_hh[1*H_ + lane];
    const float bxn = b_ih[2*H_ + lane];   // stays separate: n = tanh(xn + r*hn)
    const float bhn = b_hh[2*H_ + lane];

    const float* xb0 = x1 + (size_t)seq * (T_ * D_);
    const float* xb1 = x2 + (size_t)seq * (T_ * D_);

    float h0 = 0.f, h1 = 0.f;
    float cx0[D_], cx1[D_];
    #pragma unroll
    for (int d = 0; d < D_; ++d) { cx0[d] = xb0[d]; cx1[d] = xb1[d]; }

    for (int t = 0; t < T_; ++t) {
        // stage h for wave-wide broadcast (wave-private region; in-order DS,
        // compiler inserts lgkmcnt waits — no barrier needed)
        lds_h[wave][0][lane] = h0;
        lds_h[wave][1][lane] = h1;

        // prefetch next step's x (wave-uniform scalar loads)
        const int tn = (t + 1 < T_) ? (t + 1) : t;
        float nx0[D_], nx1[D_];
        #pragma unroll
        for (int d = 0; d < D_; ++d) {
            nx0[d] = xb0[tn * D_ + d];
            nx1[d] = xb1[tn * D_ + d];
        }

        float ar0 = brz, az0 = bzz, an0 = bxn, ah0 = bhn;
        float ar1 = brz, az1 = bzz, an1 = bxn, ah1 = bhn;
        #pragma unroll
        for (int d = 0; d < D_; ++d) {
            ar0 += cx0[d] * wxr[d]; az0 += cx0[d] * wxz[d]; an0 += cx0[d] * wxn[d];
            ar1 += cx1[d] * wxr[d]; az1 += cx1[d] * wxz[d]; an1 += cx1[d] * wxn[d];
        }

        // recurrent matmul: 16 broadcast b128 reads/chain + 192 FMA/chain
        #pragma unroll
        for (int k4 = 0; k4 < H_ / 4; ++k4) {
            const float4 v0 = *(const float4*)&lds_h[wave][0][4*k4];
            const float4 v1 = *(const float4*)&lds_h[wave][1][4*k4];
            const float hv0[4] = {v0.x, v0.y, v0.z, v0.w};
            const float hv1[4] = {v1.x, v1.y, v1.z, v1.w};
            #pragma unroll
            for (int kk = 0; kk < 4; ++kk) {
                const int k = 4*k4 + kk;
                ar0 += hv0[kk] * wr[k]; az0 += hv0[kk] * wz[k]; ah0 += hv0[kk] * wn[k];
                ar1 += hv1[kk] * wr[k]; az1 += hv1[kk] * wz[k]; ah1 += hv1[kk] * wn[k];
            }
        }

        const float r0g = fast_sigmoid(ar0);
        const float r1g = fast_sigmoid(ar1);
        const float z0g = fast_sigmoid(az0);
        const float z1g = fast_sigmoid(az1);
        const float n0g = fast_tanh(an0 + r0g * ah0);
        const float n1g = fast_tanh(an1 + r1g * ah1);
        h0 = n0g + z0g * (h0 - n0g);
        h1 = n1g + z1g * (h1 - n1g);

        #pragma unroll
        for (int d = 0; d < D_; ++d) { cx0[d] = nx0[d]; cx1[d] = nx1[d]; }
    }

    // ---- epilogue: diff -> Linear(64,32)+ReLU -> Linear(32,1)+sigmoid ----
    __shared__ float lds_d[WPB][H_];
    lds_d[wave][lane] = fabsf(h0 - h1);   // same-wave write->read, in-order

    float contrib = 0.f;
    if (lane < 32) {
        float acc = b1[lane];
        const float4* w1r = (const float4*)(W1 + lane * H_);
        #pragma unroll
        for (int k = 0; k < H_ / 4; ++k) {
            float4 w = w1r[k];
            acc += w.x * lds_d[wave][4*k+0] + w.y * lds_d[wave][4*k+1]
                 + w.z * lds_d[wave][4*k+2] + w.w * lds_d[wave][4*k+3];
        }
        acc = fmaxf(acc, 0.f);
        contrib = acc * W2[lane];
    }
    #pragma unroll
    for (int off = 32; off > 0; off >>= 1) contrib += __shfl_down(contrib, off);
    if (lane == 0) out[seq] = fast_sigmoid(contrib + b2[0]);
}

extern "C" void kernel_launch(void* const* d_in, const int* in_sizes, int n_in,
                              void* d_out, int out_size, void* d_ws, size_t ws_size,
                              hipStream_t stream) {
    const float* x1   = (const float*)d_in[0];
    const float* x2   = (const float*)d_in[1];
    const float* W_ih = (const float*)d_in[2];
    const float* W_hh = (const float*)d_in[3];
    const float* b_ih = (const float*)d_in[4];
    const float* b_hh = (const float*)d_in[5];
    const float* W1   = (const float*)d_in[6];
    const float* b1   = (const float*)d_in[7];
    const float* W2   = (const float*)d_in[8];
    const float* b2   = (const float*)d_in[9];

    const int B = in_sizes[0] / (T_ * D_);      // 4096
    dim3 grid(B / WPB), block(64 * WPB);
    gru_siamese<<<grid, block, 0, stream>>>(x1, x2, W_ih, W_hh, b_ih, b_hh,
                                            W1, b1, W2, b2, (float*)d_out);
}

// Round 2
// 1499.270 us; speedup vs baseline: 2.4547x; 2.4547x over previous
//
#include <hip/hip_runtime.h>
#include <math.h>

#define T_ 1024
#define D_ 3
#define H_ 64

typedef _Float16 f16x8 __attribute__((ext_vector_type(8)));
typedef float f32x4 __attribute__((ext_vector_type(4)));

__device__ __forceinline__ float sigmoid_f(float x) {
    return __builtin_amdgcn_rcpf(1.0f + __expf(-x));
}
__device__ __forceinline__ float tanh_f(float x) {
    float e = __expf(2.0f * x);
    return 1.0f - 2.0f * __builtin_amdgcn_rcpf(e + 1.0f);
}

// One wave per block. Wave handles 16 batch rows: rows 0..7 = chain-1 (x1) of
// seqs [seq0, seq0+8), rows 8..15 = chain-2 (x2) of the same seqs.
// Recurrent matmul per step via mfma_f32_16x16x32_f16:
//   A = h [16 x 64] (f16, LDS round-trip), B = W_hh^T tiles (static, 96 VGPRs),
//   C/D = gate preacts [16 x 192] in fp32, D-layout col=lane&15,row=quad*4+reg.
// Gate math + h-update in fp32 VALU at D-layout positions. x-part (D=3) folded
// into MFMA-C initialization. Siamese diff via shfl_xor(·,32); MLP in-wave.
__global__ __launch_bounds__(64, 1) void gru_mfma(
    const float* __restrict__ x1, const float* __restrict__ x2,
    const float* __restrict__ W_ih, const float* __restrict__ W_hh,
    const float* __restrict__ b_ih, const float* __restrict__ b_hh,
    const float* __restrict__ W1, const float* __restrict__ b1,
    const float* __restrict__ W2, const float* __restrict__ b2,
    float* __restrict__ out)
{
    const int lane = threadIdx.x & 63;
    const int c = lane & 15;          // A-operand m / C-D col / B-operand n
    const int q = lane >> 4;          // quad
    const int seq0 = blockIdx.x * 8;

    // ---- static weight B-fragments: B[k][n] = W_hh[16*nt+c][32*ks+q*8+j] ----
    f16x8 wf[12][2];
    #pragma unroll
    for (int nt = 0; nt < 12; ++nt) {
        #pragma unroll
        for (int ks = 0; ks < 2; ++ks) {
            const float* p = W_hh + (16 * nt + c) * H_ + 32 * ks + q * 8;
            f16x8 v;
            #pragma unroll
            for (int j = 0; j < 8; ++j) v[j] = (_Float16)p[j];
            wf[nt][ks] = v;
        }
    }

    // x-weights + biases for this lane's 12 gate columns (g = 16*nt + c)
    float wx[12][3];
    #pragma unroll
    for (int nt = 0; nt < 12; ++nt) {
        #pragma unroll
        for (int d = 0; d < 3; ++d) wx[nt][d] = W_ih[(16 * nt + c) * D_ + d];
    }
    float comb[8];                    // r,z: b_ih + b_hh combined
    #pragma unroll
    for (int nt = 0; nt < 8; ++nt) comb[nt] = b_ih[16 * nt + c] + b_hh[16 * nt + c];
    float bxn[4], bhn[4];             // n-gate: keep separate (r multiplies hn+bhn)
    #pragma unroll
    for (int jt = 0; jt < 4; ++jt) {
        bxn[jt] = b_ih[128 + 16 * jt + c];
        bhn[jt] = b_hh[128 + 16 * jt + c];
    }

    // x pointers for this lane's 4 rows (m = q*4 + r)
    const float* xp[4];
    #pragma unroll
    for (int r = 0; r < 4; ++r) {
        const int m = q * 4 + r;
        xp[r] = (m < 8) ? (x1 + (size_t)(seq0 + m) * (T_ * D_))
                        : (x2 + (size_t)(seq0 + m - 8) * (T_ * D_));
    }

    // LDS: h16 in A-frag-friendly [m][k] layout, row stride 72 halves (2-way max)
    __shared__ _Float16 hlds[16 * 72];
    __shared__ float dlds[8][68];

    float h[4][4];                    // [jt][r] : h[row=q*4+r][col=16*jt+c]
    #pragma unroll
    for (int jt = 0; jt < 4; ++jt)
        #pragma unroll
        for (int r = 0; r < 4; ++r) h[jt][r] = 0.f;

    // x double-buffer, prefetch distance 2
    float xa[4][3], xb[4][3];
    #pragma unroll
    for (int r = 0; r < 4; ++r)
        #pragma unroll
        for (int d = 0; d < 3; ++d) {
            xa[r][d] = xp[r][0 * D_ + d];
            xb[r][d] = xp[r][1 * D_ + d];
        }

    auto step = [&](float (&xc)[4][3], int tld) {
        // ---- C init: bias + x-part (consumes xc) ----
        f32x4 acc[12];
        float xnv[4][4];
        #pragma unroll
        for (int nt = 0; nt < 8; ++nt) {
            #pragma unroll
            for (int r = 0; r < 4; ++r)
                acc[nt][r] = comb[nt] + xc[r][0] * wx[nt][0]
                           + xc[r][1] * wx[nt][1] + xc[r][2] * wx[nt][2];
        }
        #pragma unroll
        for (int jt = 0; jt < 4; ++jt) {
            #pragma unroll
            for (int r = 0; r < 4; ++r) {
                acc[8 + jt][r] = bhn[jt];
                xnv[jt][r] = bxn[jt] + xc[r][0] * wx[8 + jt][0]
                           + xc[r][1] * wx[8 + jt][1] + xc[r][2] * wx[8 + jt][2];
            }
        }
        // ---- prefetch x(t+2) into the buffer just consumed ----
        if (tld < T_) {
            #pragma unroll
            for (int r = 0; r < 4; ++r)
                #pragma unroll
                for (int d = 0; d < 3; ++d) xc[r][d] = xp[r][tld * D_ + d];
        }
        // ---- h -> LDS (f16), then A-fragments ----
        #pragma unroll
        for (int jt = 0; jt < 4; ++jt)
            #pragma unroll
            for (int r = 0; r < 4; ++r)
                hlds[(q * 4 + r) * 72 + 16 * jt + c] = (_Float16)h[jt][r];
        const f16x8 a0 = *(const f16x8*)&hlds[c * 72 + q * 8];        // k 0..31
        const f16x8 a1 = *(const f16x8*)&hlds[c * 72 + 32 + q * 8];   // k 32..63
        // ---- 24 MFMAs: 12 N-tiles x 2 k-steps ----
        #pragma unroll
        for (int nt = 0; nt < 12; ++nt) {
            acc[nt] = __builtin_amdgcn_mfma_f32_16x16x32_f16(a0, wf[nt][0], acc[nt], 0, 0, 0);
            acc[nt] = __builtin_amdgcn_mfma_f32_16x16x32_f16(a1, wf[nt][1], acc[nt], 0, 0, 0);
        }
        // ---- gates + h update (fp32, D-layout positions) ----
        #pragma unroll
        for (int jt = 0; jt < 4; ++jt) {
            #pragma unroll
            for (int r = 0; r < 4; ++r) {
                const float rr = sigmoid_f(acc[jt][r]);
                const float zz = sigmoid_f(acc[4 + jt][r]);
                const float nn = tanh_f(xnv[jt][r] + rr * acc[8 + jt][r]);
                h[jt][r] = nn + zz * (h[jt][r] - nn);
            }
        }
    };

    for (int t = 0; t < T_; t += 2) {
        step(xa, t + 2);
        step(xb, t + 3);
    }

    // ---- epilogue: |h1 - h2| -> Linear(64,32)+ReLU -> Linear(32,1)+sigmoid ----
    float dv[4][4];
    #pragma unroll
    for (int jt = 0; jt < 4; ++jt)
        #pragma unroll
        for (int r = 0; r < 4; ++r) {
            const float o = __shfl_xor(h[jt][r], 32);
            dv[jt][r] = fabsf(h[jt][r] - o);
        }
    if (lane < 32) {   // quads 0,1 hold rows 0..7 (= seqs seq0..seq0+7)
        #pragma unroll
        for (int jt = 0; jt < 4; ++jt)
            #pragma unroll
            for (int r = 0; r < 4; ++r)
                dlds[q * 4 + r][16 * jt + c] = dv[jt][r];
    }
    // same-wave LDS write->read: in-order, no barrier needed
    const int s = lane >> 3;   // seq within block
    const int b = lane & 7;    // hidden-unit group base
    float am[4];
    #pragma unroll
    for (int i = 0; i < 4; ++i) am[i] = b1[b + 8 * i];
    #pragma unroll
    for (int k4 = 0; k4 < 16; ++k4) {
        const float4 dvec = *(const float4*)&dlds[s][k4 * 4];
        #pragma unroll
        for (int i = 0; i < 4; ++i) {
            const float4 w = *(const float4*)&W1[(b + 8 * i) * H_ + k4 * 4];
            am[i] += dvec.x * w.x + dvec.y * w.y + dvec.z * w.z + dvec.w * w.w;
        }
    }
    float part = 0.f;
    #pragma unroll
    for (int i = 0; i < 4; ++i) part += fmaxf(am[i], 0.f) * W2[b + 8 * i];
    part += __shfl_xor(part, 1);
    part += __shfl_xor(part, 2);
    part += __shfl_xor(part, 4);
    if (b == 0) out[seq0 + s] = sigmoid_f(part + b2[0]);
}

extern "C" void kernel_launch(void* const* d_in, const int* in_sizes, int n_in,
                              void* d_out, int out_size, void* d_ws, size_t ws_size,
                              hipStream_t stream) {
    const float* x1   = (const float*)d_in[0];
    const float* x2   = (const float*)d_in[1];
    const float* W_ih = (const float*)d_in[2];
    const float* W_hh = (const float*)d_in[3];
    const float* b_ih = (const float*)d_in[4];
    const float* b_hh = (const float*)d_in[5];
    const float* W1   = (const float*)d_in[6];
    const float* b1   = (const float*)d_in[7];
    const float* W2   = (const float*)d_in[8];
    const float* b2   = (const float*)d_in[9];

    const int B = in_sizes[0] / (T_ * D_);      // 4096
    dim3 grid(B / 8), block(64);
    gru_mfma<<<grid, block, 0, stream>>>(x1, x2, W_ih, W_hh, b_ih, b_hh,
                                         W1, b1, W2, b2, (float*)d_out);
}

// Round 3
// 703.912 us; speedup vs baseline: 5.2283x; 2.1299x over previous
//
#include <hip/hip_runtime.h>
#include <math.h>

#define T_ 1024
#define D_ 3
#define H_ 64

typedef _Float16 f16x8 __attribute__((ext_vector_type(8)));
typedef float f32x4 __attribute__((ext_vector_type(4)));

__device__ __forceinline__ float sigmoid_f(float x) {
    return __builtin_amdgcn_rcpf(1.0f + __expf(-x));
}
__device__ __forceinline__ float tanh_f(float x) {
    float e = __expf(2.0f * x);
    return 1.0f - 2.0f * __builtin_amdgcn_rcpf(e + 1.0f);
}

#define MFMA(A, B, C) __builtin_amdgcn_mfma_f32_16x16x32_f16((A), (B), (C), 0, 0, 0)

// 4 waves/block cooperate on one 16-row group (8 seqs x 2 Siamese chains).
// Wave w owns hidden units [16w,16w+16): 3 N-tiles (r,z,n gates for its units).
// Per step: h-tile broadcast via LDS (double-buffered, ONE barrier/step);
// 9 MFMAs/wave (6 h-part + 3 x/bias-part via k-extension fragment, biases as
// C-operand splats -> zero VALU C-init); gate math = 4 elements/lane fp32.
__global__ __launch_bounds__(256, 2) void gru_mfma4(
    const float* __restrict__ x1, const float* __restrict__ x2,
    const float* __restrict__ W_ih, const float* __restrict__ W_hh,
    const float* __restrict__ b_ih, const float* __restrict__ b_hh,
    const float* __restrict__ W1, const float* __restrict__ b1,
    const float* __restrict__ W2, const float* __restrict__ b2,
    float* __restrict__ out)
{
    const int lane = threadIdx.x & 63;
    const int w    = threadIdx.x >> 6;   // wave 0..3: owns units 16w..16w+15
    const int c    = lane & 15;          // A-m / C-D col / B-n
    const int q    = lane >> 4;          // quad
    const int u    = 16 * w + c;         // this lane's hidden-unit column
    const int seq0 = blockIdx.x * 8;

    // ---- h-part B-fragments: wf[g][ks][j] = W_hh[g*64+u][32*ks+q*8+j] ----
    f16x8 wf[3][2];
    #pragma unroll
    for (int g = 0; g < 3; ++g)
        #pragma unroll
        for (int ks = 0; ks < 2; ++ks) {
            const float* p = W_hh + (size_t)(g * 64 + u) * H_ + 32 * ks + q * 8;
            f16x8 v;
            #pragma unroll
            for (int j = 0; j < 8; ++j) v[j] = (_Float16)p[j];
            wf[g][ks] = v;
        }

    // ---- x-part B-fragments (k=0..2 live in q==0 lanes only) ----
    f16x8 bxf[3];
    #pragma unroll
    for (int g = 0; g < 3; ++g) {
        f16x8 v = {};
        if (q == 0) {
            #pragma unroll
            for (int d = 0; d < 3; ++d)
                v[d] = (_Float16)W_ih[(size_t)(g * 64 + u) * D_ + d];
        }
        bxf[g] = v;
    }

    // ---- bias C-splats ----
    const float comb_r = b_ih[u]        + b_hh[u];
    const float comb_z = b_ih[64 + u]   + b_hh[64 + u];
    const float bxn    = b_ih[128 + u];
    const float bhn    = b_hh[128 + u];
    const f32x4 Cr  = {comb_r, comb_r, comb_r, comb_r};
    const f32x4 Cz  = {comb_z, comb_z, comb_z, comb_z};
    const f32x4 Cxn = {bxn, bxn, bxn, bxn};
    const f32x4 Chn = {bhn, bhn, bhn, bhn};

    // ---- x pointer for "row c" (rows 0..7 = chain1, 8..15 = chain2) ----
    const float* xptr = (c < 8) ? (x1 + (size_t)(seq0 + c) * (T_ * D_))
                                : (x2 + (size_t)(seq0 + c - 8) * (T_ * D_));

    // h-tile double buffer: [row][unit], stride 72 halves (b128-aligned reads)
    __shared__ alignas(16) _Float16 hb[2][16 * 72];
    __shared__ float dlds[8][68];

    float h[4];                       // h[row=q*4+r][unit u]
    #pragma unroll
    for (int r = 0; r < 4; ++r) h[r] = 0.f;

    float xv0[3], xv1[3];             // x(t), x(t+1); prefetch distance 2
    #pragma unroll
    for (int d = 0; d < 3; ++d) { xv0[d] = xptr[d]; xv1[d] = xptr[D_ + d]; }

    auto step = [&](int buf, float (&xc)[3], int tld) {
        // x k-extension A-fragment (q==0 lanes carry x at k=0..2)
        f16x8 ax = {};
        if (q == 0) {
            ax[0] = (_Float16)xc[0]; ax[1] = (_Float16)xc[1]; ax[2] = (_Float16)xc[2];
        }
        // prefetch x(t+2) into the slot just consumed
        if (tld < T_) {
            #pragma unroll
            for (int d = 0; d < 3; ++d) xc[d] = xptr[tld * D_ + d];
        }
        // publish h(t) (f16) to this step's buffer
        #pragma unroll
        for (int r = 0; r < 4; ++r)
            hb[buf][(q * 4 + r) * 72 + u] = (_Float16)h[r];
        __syncthreads();
        const f16x8 a0 = *(const f16x8*)&hb[buf][c * 72 + q * 8];        // k 0..31
        const f16x8 a1 = *(const f16x8*)&hb[buf][c * 72 + 32 + q * 8];   // k 32..63

        f32x4 ar  = MFMA(ax, bxf[0], Cr);
        f32x4 az  = MFMA(ax, bxf[1], Cz);
        f32x4 axn = MFMA(ax, bxf[2], Cxn);
        f32x4 ahn = MFMA(a0, wf[2][0], Chn);
        ar  = MFMA(a0, wf[0][0], ar);
        az  = MFMA(a0, wf[1][0], az);
        ahn = MFMA(a1, wf[2][1], ahn);
        ar  = MFMA(a1, wf[0][1], ar);
        az  = MFMA(a1, wf[1][1], az);

        #pragma unroll
        for (int r = 0; r < 4; ++r) {
            const float rr = sigmoid_f(ar[r]);
            const float zz = sigmoid_f(az[r]);
            const float nn = tanh_f(axn[r] + rr * ahn[r]);
            h[r] = nn + zz * (h[r] - nn);
        }
    };

    for (int t = 0; t < T_; t += 2) {
        step(0, xv0, t + 2);
        step(1, xv1, t + 3);
    }

    // ---- epilogue: |h1-h2| -> Linear(64,32)+ReLU -> Linear(32,1)+sigmoid ----
    #pragma unroll
    for (int r = 0; r < 4; ++r) {
        const float o = __shfl_xor(h[r], 32);     // row m <-> m+8 (q ^= 2)
        if (q < 2) dlds[q * 4 + r][u] = fabsf(h[r] - o);
    }
    __syncthreads();
    if (w == 0) {
        const int s = lane >> 3;   // seq within block 0..7
        const int b = lane & 7;    // hidden-row group base
        float am[4];
        #pragma unroll
        for (int i = 0; i < 4; ++i) am[i] = b1[b + 8 * i];
        #pragma unroll
        for (int k4 = 0; k4 < 16; ++k4) {
            const float4 dvec = *(const float4*)&dlds[s][k4 * 4];
            #pragma unroll
            for (int i = 0; i < 4; ++i) {
                const float4 wv = *(const float4*)&W1[(b + 8 * i) * H_ + k4 * 4];
                am[i] += dvec.x * wv.x + dvec.y * wv.y + dvec.z * wv.z + dvec.w * wv.w;
            }
        }
        float part = 0.f;
        #pragma unroll
        for (int i = 0; i < 4; ++i) part += fmaxf(am[i], 0.f) * W2[b + 8 * i];
        part += __shfl_xor(part, 1);
        part += __shfl_xor(part, 2);
        part += __shfl_xor(part, 4);
        if (b == 0) out[seq0 + s] = sigmoid_f(part + b2[0]);
    }
}

extern "C" void kernel_launch(void* const* d_in, const int* in_sizes, int n_in,
                              void* d_out, int out_size, void* d_ws, size_t ws_size,
                              hipStream_t stream) {
    const float* x1   = (const float*)d_in[0];
    const float* x2   = (const float*)d_in[1];
    const float* W_ih = (const float*)d_in[2];
    const float* W_hh = (const float*)d_in[3];
    const float* b_ih = (const float*)d_in[4];
    const float* b_hh = (const float*)d_in[5];
    const float* W1   = (const float*)d_in[6];
    const float* b1   = (const float*)d_in[7];
    const float* W2   = (const float*)d_in[8];
    const float* b2   = (const float*)d_in[9];

    const int B = in_sizes[0] / (T_ * D_);      // 4096
    dim3 grid(B / 8), block(256);
    gru_mfma4<<<grid, block, 0, stream>>>(x1, x2, W_ih, W_hh, b_ih, b_hh,
                                          W1, b1, W2, b2, (float*)d_out);
}